// Round 8
// baseline (402.574 us; speedup 1.0000x reference)
//
#include <hip/hip_runtime.h>
#include <hip/hip_cooperative_groups.h>
#include <math.h>

namespace cg = cooperative_groups;

#define B_   128
#define N_   50
#define D_   64
#define BN   6400        // B*N
#define EPSF 1e-5f
// F(1,254) upper 0.05 critical value: pval > 0.05  <=>  fstat < FCRIT
#define FCRIT 3.8783305f

__device__ __forceinline__ float wsum(float v){
#pragma unroll
  for(int o=32;o>0;o>>=1) v += __shfl_xor(v,o);
  return v;
}
__device__ __forceinline__ float wmax(float v){
#pragma unroll
  for(int o=32;o>0;o>>=1) v = fmaxf(v,__shfl_xor(v,o));
  return v;
}
__device__ __forceinline__ float leaky(float x){ return x >= 0.f ? x : 0.2f*x; }

// One cooperative kernel: 256 blocks = 2 per batch (25 dst nodes each).
// Everything batch-local stays in LDS; only acc/stats cross blocks.
__global__ __launch_bounds__(512) void fused(
    const float* __restrict__ x, const float* __restrict__ labels,
    const float* __restrict__ emb, const float* __restrict__ W,
    const float* __restrict__ att_i, const float* __restrict__ att_j,
    const float* __restrict__ att_em_i, const float* __restrict__ att_em_j,
    const float* __restrict__ gat_bias,
    const float* __restrict__ bn1_g, const float* __restrict__ bn1_b,
    const float* __restrict__ bn1_rm, const float* __restrict__ bn1_rv,
    const float* __restrict__ bn2_g, const float* __restrict__ bn2_b,
    const float* __restrict__ bn2_rm, const float* __restrict__ bn2_rv,
    const float* __restrict__ out_w, const float* __restrict__ out_b,
    float2* __restrict__ acc, float* __restrict__ stats1,
    float* __restrict__ stats2, float4* __restrict__ hc4,
    float* __restrict__ hci2g, float* __restrict__ outp){
  __shared__ float wl[64*64];      // W
  __shared__ float xl[50*65];      // x rows, padded (conflict-free 4-q read)
  __shared__ float hT[64*53];      // h transposed [d][q], stride-53
  __shared__ float sl_i[64], sl_j[64];
  __shared__ float el[8*64];       // per-wave e_q scratch (reused P3)
  __shared__ float2 wc[8*64];      // per-wave (S_d, Em_d)
  __shared__ int   keepL[8*64];
  __shared__ float outL[25*64];    // this block's out_raw rows
  __shared__ float2 red[8][64];

  cg::grid_group grid = cg::this_grid();
  int tid = threadIdx.x, w = tid>>6, lane = tid&63;
  int blk = blockIdx.x;
  int b = blk>>1, p0 = (blk&1)*25;

  // ---- P1: stage W, x; block 0 zeroes globals and folds eval constants ----
  { const float4* W4 = (const float4*)W;
    float4* wl4 = (float4*)wl;
    for(int i=tid;i<1024;i+=512) wl4[i] = W4[i]; }
  { const float* xb = x + (size_t)b*N_*64;
    for(int i=tid;i<3200;i+=512) xl[(i>>6)*65 + (i&63)] = xb[i]; }
  if(blk==0){
    for(int i=tid;i<N_*N_;i+=512) acc[i] = make_float2(0.f,0.f);
    for(int i=tid;i<1024;i+=512){ stats1[i]=0.f; stats2[i]=0.f; }
    if(tid<64){
      float i1g = bn1_g[tid]/sqrtf(bn1_rv[tid]+EPSF);
      float i2g = bn2_g[tid]/sqrtf(bn2_rv[tid]+EPSF);
      float C1 = i1g*gat_bias[tid] + bn1_b[tid] - bn1_rm[tid]*i1g;
      float C2 = bn2_b[tid] - bn2_rm[tid]*i2g;
      hc4[tid] = make_float4(i1g, C1, C2, out_w[tid]);
      hci2g[tid] = i2g;
    }
  }
  __syncthreads();

  // ---- P1b: hT[d][q] = (x @ W)[q][d]; thread computes 4 d's for one q ----
#pragma unroll
  for(int it=0; it<2; ++it){
    int idx4 = tid + it*512;
    if(idx4 < 800){
      int q = idx4 >> 4, d4 = idx4 & 15;
      const float4* wrow = (const float4*)wl;
      float4 a = make_float4(0.f,0.f,0.f,0.f);
#pragma unroll
      for(int k=0;k<64;k++){
        float xv = xl[q*65+k];           // 4 q's/wave, padded: conflict-free
        float4 wv = wrow[k*16+d4];       // b128, stride-1
        a.x=fmaf(xv,wv.x,a.x); a.y=fmaf(xv,wv.y,a.y);
        a.z=fmaf(xv,wv.z,a.z); a.w=fmaf(xv,wv.w,a.w);
      }
      int d0 = d4*4;
      hT[(d0  )*53+q]=a.x; hT[(d0+1)*53+q]=a.y;
      hT[(d0+2)*53+q]=a.z; hT[(d0+3)*53+q]=a.w;
    }
  }
  __syncthreads();

  // ---- P1c: s_i, s_j per node (wave per q) ----
  for(int q=w; q<N_; q+=8){
    float hv = hT[lane*53+q];
    float ev = emb[q*64+lane];
    float si = wsum(fmaf(hv, att_i[lane], ev*att_em_i[lane]));
    float sj = wsum(fmaf(hv, att_j[lane], ev*att_em_j[lane]));
    if(lane==0){ sl_i[q]=si; sl_j[q]=sj; }
  }
  __syncthreads();
  __threadfence();
  grid.sync();                         // globals zeroed + hc4 ready

  // ---- P2: 50 submodel preds per (b,p) via one-term deletion; moments ----
  float ob = out_b[0];
  for(int pi=w; pi<25; pi+=8){
    int p = p0 + pi;
    float sip = sl_i[p];
    float L = -3.0e38f;
    if(lane<N_) L = leaky(sip + sl_j[lane]);
    float M = wmax(L);
    float e = (lane<N_) ? expf(L-M) : 0.f;
    float Dden = wsum(e);
    el[w*64+lane] = e;
    float S = 0.f;
    const float* hTd = &hT[lane*53];
    const float* elw = &el[w*64];
#pragma unroll 10
    for(int q=0;q<N_;q++) S = fmaf(elw[q], hTd[q], S);
    wc[w*64+lane] = make_float2(S, emb[p*64+lane]*hci2g[lane]);
    // lane = submodel
    float er = 0.f; int r = 0;
    if(lane>=1 && lane<N_){ int s=lane-1; r = s + (s>=p?1:0); er = el[w*64+r]; }
    float beta  = 1.f/(Dden - er);
    float alpha = er*beta;
    float a_ = ob;
    const float2* wcw = &wc[w*64];
#pragma unroll 8
    for(int d=0;d<64;d++){
      float4 hc = hc4[d];              // uniform -> scalar load
      float2 se = wcw[d];              // LDS broadcast
      float hrd = hT[d*53 + r];        // lane-varying, <=2-way
      float o  = fmaf(-alpha, hrd, se.x*beta);
      float g  = fmaxf(fmaf(hc.x, o, hc.y), 0.f);
      float xn = fmaxf(fmaf(g, se.y, hc.z), 0.f);
      a_ = fmaf(xn, hc.w, a_);
    }
    if(lane<N_){
      float resid = labels[b*N_+p] - a_;
      atomicAdd(&acc[p*N_+lane].x, resid);
      atomicAdd(&acc[p*N_+lane].y, resid*resid);
    }
  }
  __threadfence();
  grid.sync();                         // acc complete

  // ---- P3: inline F-test -> masked attention -> outL; Σo,Σo² ----
  float s1=0.f, s2=0.f;
  for(int pi=w; pi<25; pi+=8){
    int p = p0 + pi;
    int kb = 1;
    if(lane < N_-1){
      float2 A2 = acc[p*N_ + lane + 1];
      float2 B2 = acc[p*N_];
      float ma = A2.x*(1.f/B_), mb = B2.x*(1.f/B_);
      float ssw = (A2.y - (float)B_*ma*ma) + (B2.y - (float)B_*mb*mb);
      float dmb = ma - mb;
      float f = (64.f*dmb*dmb) / (ssw*(1.f/254.f));
      kb = (f < FCRIT) ? 0 : 1;        // NaN -> keep (matches reference)
    }
    keepL[w*64+lane] = kb;             // same-wave write/read
    float sip = sl_i[p];
    float L = -3.0e38f; bool allowed = false;
    if(lane<N_){
      float Lr = leaky(sip + sl_j[lane]);
      if(lane==p) allowed = true;
      else { int idx = (lane<p)?lane:lane-1; allowed = keepL[w*64+idx]!=0; }
      L = allowed ? Lr : -1.0e9f;
    }
    float M = wmax(L);
    float e = allowed ? expf(L-M) : 0.f;
    float Dn = wsum(e);
    el[w*64+lane] = e;
    float invD = 1.f/Dn;
    float s = 0.f;
    const float* hTd = &hT[lane*53];
    const float* elw = &el[w*64];
#pragma unroll 10
    for(int q=0;q<N_;q++) s = fmaf(elw[q], hTd[q], s);
    float o = fmaf(s, invD, gat_bias[lane]);
    outL[pi*64+lane] = o;
    s1 += o; s2 = fmaf(o,o,s2);
  }
  red[w][lane] = make_float2(s1,s2);
  __syncthreads();
  if(w==0){
    float a1=0.f, a2=0.f;
#pragma unroll
    for(int k=0;k<8;k++){ float2 v = red[k][lane]; a1+=v.x; a2+=v.y; }
    int slot = blk & 7;
    atomicAdd(&stats1[slot*128 + lane],      a1);
    atomicAdd(&stats1[slot*128 + 64 + lane], a2);
  }
  __threadfence();
  grid.sync();                         // stats1 complete

  // ---- P4: train-BN1 fold; Σx3, Σx3² ----
  float t1=0.f, t2=0.f;
#pragma unroll
  for(int k=0;k<8;k++){ t1 += stats1[k*128+lane]; t2 += stats1[k*128+64+lane]; }
  float mu1  = t1*(1.f/BN), var1 = t2*(1.f/BN) - mu1*mu1;
  float A1 = bn1_g[lane]/sqrtf(var1+EPSF);
  float C1 = bn1_b[lane] - mu1*A1;
  s1=0.f; s2=0.f;
  for(int pi=w; pi<25; pi+=8){
    int p = p0 + pi;
    float o  = outL[pi*64+lane];
    float g  = fmaxf(fmaf(A1,o,C1), 0.f);
    float x3 = g*emb[p*64+lane];
    s1 += x3; s2 = fmaf(x3,x3,s2);
  }
  red[w][lane] = make_float2(s1,s2);
  __syncthreads();
  if(w==0){
    float a1=0.f, a2=0.f;
#pragma unroll
    for(int k=0;k<8;k++){ float2 v = red[k][lane]; a1+=v.x; a2+=v.y; }
    int slot = blk & 7;
    atomicAdd(&stats2[slot*128 + lane],      a1);
    atomicAdd(&stats2[slot*128 + 64 + lane], a2);
  }
  __threadfence();
  grid.sync();                         // stats2 complete

  // ---- P5: final head ----
  float t3=0.f, t4=0.f;
#pragma unroll
  for(int k=0;k<8;k++){ t3 += stats2[k*128+lane]; t4 += stats2[k*128+64+lane]; }
  float mu2  = t3*(1.f/BN), var2 = t4*(1.f/BN) - mu2*mu2;
  float A2 = bn2_g[lane]/sqrtf(var2+EPSF);
  float C2 = bn2_b[lane] - mu2*A2;
  float ow = out_w[lane];
  for(int pi=w; pi<25; pi+=8){
    int p = p0 + pi;
    float o  = outL[pi*64+lane];
    float g  = fmaxf(fmaf(A1,o,C1), 0.f);
    float x3 = g*emb[p*64+lane];
    float xn = fmaxf(fmaf(A2,x3,C2), 0.f);
    float pr = wsum(xn*ow);
    if(lane==0) outp[b*N_+p] = pr + ob;
  }
}

extern "C" void kernel_launch(void* const* d_in, const int* in_sizes, int n_in,
                              void* d_out, int out_size, void* d_ws, size_t ws_size,
                              hipStream_t stream){
  (void)in_sizes; (void)n_in; (void)out_size; (void)ws_size;
  const float* data     = (const float*)d_in[0];
  const float* labels   = (const float*)d_in[1];
  // d_in[2..6]: graph indices / masks — deterministic, not read.
  const float* emb      = (const float*)d_in[7];
  const float* W_lin    = (const float*)d_in[8];
  const float* att_i    = (const float*)d_in[9];
  const float* att_j    = (const float*)d_in[10];
  const float* att_em_i = (const float*)d_in[11];
  const float* att_em_j = (const float*)d_in[12];
  const float* gat_bias = (const float*)d_in[13];
  const float* bn1_g    = (const float*)d_in[14];
  const float* bn1_b    = (const float*)d_in[15];
  const float* bn1_rm   = (const float*)d_in[16];
  const float* bn1_rv   = (const float*)d_in[17];
  const float* bn2_g    = (const float*)d_in[18];
  const float* bn2_b    = (const float*)d_in[19];
  const float* bn2_rm   = (const float*)d_in[20];
  const float* bn2_rv   = (const float*)d_in[21];
  const float* out_w    = (const float*)d_in[22];
  const float* out_b    = (const float*)d_in[23];

  float*  ws     = (float*)d_ws;
  float2* acc    = (float2*)ws;              // 2500 float2 = 5000 f
  float*  stats1 = ws + 5120;                // 1024
  float*  stats2 = ws + 6144;                // 1024
  float4* hc4    = (float4*)(ws + 7168);     // 64 float4 (16B aligned)
  float*  hci2g  = ws + 7424;                // 64
  float*  outp   = (float*)d_out;

  void* args[] = {
    (void*)&data, (void*)&labels, (void*)&emb, (void*)&W_lin,
    (void*)&att_i, (void*)&att_j, (void*)&att_em_i, (void*)&att_em_j,
    (void*)&gat_bias,
    (void*)&bn1_g, (void*)&bn1_b, (void*)&bn1_rm, (void*)&bn1_rv,
    (void*)&bn2_g, (void*)&bn2_b, (void*)&bn2_rm, (void*)&bn2_rv,
    (void*)&out_w, (void*)&out_b,
    (void*)&acc, (void*)&stats1, (void*)&stats2, (void*)&hc4,
    (void*)&hci2g, (void*)&outp
  };
  hipLaunchCooperativeKernel((const void*)fused, dim3(2*B_), dim3(512),
                             args, 0, stream);
}

// Round 12
// 146.876 us; speedup vs baseline: 2.7409x; 2.7409x over previous
//
#include <hip/hip_runtime.h>
#include <math.h>

#define B_   128
#define N_   50
#define FIN  64
#define D_   64
#define BN   6400        // B*N
#define EPSF 1e-5f
// F(1,254) upper 0.05 critical value: pval > 0.05  <=>  fstat < FCRIT
#define FCRIT 3.8783305f

__device__ __forceinline__ float wsum(float v){
#pragma unroll
  for(int o=32;o>0;o>>=1) v += __shfl_xor(v,o);
  return v;
}
__device__ __forceinline__ float wmax(float v){
#pragma unroll
  for(int o=32;o>0;o>>=1) v = fmaxf(v,__shfl_xor(v,o));
  return v;
}
__device__ __forceinline__ float leaky(float x){ return x >= 0.f ? x : 0.2f*x; }
// lane-broadcast from register file: v_readlane, no LDS op
__device__ __forceinline__ float rdl(float v, int l){
  return __uint_as_float(__builtin_amdgcn_readlane(__float_as_uint(v), l));
}

// K1: h = x @ W_lin; s_i, s_j per node. 8 rows/block.
// Block 0 additionally: fold eval-BN/head constants, zero acc + stats slots.
__global__ __launch_bounds__(256) void k1_lin(
    const float* __restrict__ x, const float* __restrict__ W,
    const float* __restrict__ emb,
    const float* __restrict__ att_i, const float* __restrict__ att_j,
    const float* __restrict__ att_em_i, const float* __restrict__ att_em_j,
    const float* __restrict__ bn1_g, const float* __restrict__ bn1_b,
    const float* __restrict__ bn1_rm, const float* __restrict__ bn1_rv,
    const float* __restrict__ bn2_g, const float* __restrict__ bn2_b,
    const float* __restrict__ bn2_rm, const float* __restrict__ bn2_rv,
    const float* __restrict__ gat_bias, const float* __restrict__ out_w,
    float* __restrict__ h, float* __restrict__ s_i, float* __restrict__ s_j,
    float2* __restrict__ acc, float* __restrict__ statz /*2048*/,
    float4* __restrict__ hc4, float* __restrict__ hci2g){
  __shared__ float wl[FIN*D_];
  __shared__ float xl[8*FIN];
  int tid = threadIdx.x;
  const float4* W4 = (const float4*)W;
  float4* wl4 = (float4*)wl;
  for(int i=tid;i<FIN*D_/4;i+=256) wl4[i] = W4[i];
  int r0 = blockIdx.x*8;
  { const float4* x4 = (const float4*)(x + (size_t)r0*FIN);
    float4* xl4 = (float4*)xl;
    for(int i=tid;i<8*FIN/4;i+=256) xl4[i] = x4[i]; }
  __syncthreads();
  int w = tid>>6, d = tid&63;
  float acc0 = 0.f, acc1 = 0.f;
#pragma unroll
  for(int k=0;k<FIN;k++){
    float wv = wl[k*D_+d];
    acc0 = fmaf(xl[(w*2+0)*FIN+k], wv, acc0);
    acc1 = fmaf(xl[(w*2+1)*FIN+k], wv, acc1);
  }
  float ai = att_i[d], aj = att_j[d], aei = att_em_i[d], aej = att_em_j[d];
#pragma unroll
  for(int j=0;j<2;j++){
    int r = r0 + w*2 + j;
    float a_ = j ? acc1 : acc0;
    h[(size_t)r*D_+d] = a_;
    int n = r % N_;
    float e = emb[n*D_+d];
    float si = wsum(a_*ai + e*aei);
    float sj = wsum(a_*aj + e*aej);
    if(d==0){ s_i[r]=si; s_j[r]=sj; }
  }
  if(blockIdx.x==0){
    for(int i=tid;i<N_*N_;i+=256) acc[i] = make_float2(0.f,0.f);
    for(int i=tid;i<2048;i+=256)  statz[i] = 0.f;
    if(tid < 64){
      float i1g = bn1_g[tid]/sqrtf(bn1_rv[tid]+EPSF);
      float i2g = bn2_g[tid]/sqrtf(bn2_rv[tid]+EPSF);
      float C1 = i1g*gat_bias[tid] + bn1_b[tid] - bn1_rm[tid]*i1g;
      float C2 = bn2_b[tid] - bn2_rm[tid]*i2g;
      hc4[tid] = make_float4(i1g, C1, C2, out_w[tid]);
      hci2g[tid] = i2g;
    }
  }
}

// K2: per (b,p): softmax state once; 50 submodel preds by one-term deletion;
// residual moments atomically into acc[p*50+sm]. Broadcasts via v_readlane.
__global__ __launch_bounds__(512) void k2_preds(
    const float* __restrict__ h, const float* __restrict__ s_i,
    const float* __restrict__ s_j, const float* __restrict__ labels,
    const float* __restrict__ emb, const float* __restrict__ out_b,
    const float4* __restrict__ hc4, const float* __restrict__ hci2g,
    float2* __restrict__ acc){
  __shared__ float hR[N_*65];      // row-major, stride 65 (odd -> <=2-way)
  __shared__ float el[8*64];
  int b = blockIdx.y, tid = threadIdx.x;
  const float* hb = h + (size_t)b*N_*D_;
  for(int i=tid;i<N_*D_;i+=512) hR[(i>>6)*65 + (i&63)] = hb[i];
  __syncthreads();
  int w = tid>>6, lane = tid&63;
  int p = blockIdx.x*8 + w;
  if(p >= N_) return;               // no further barriers below
  // Phase A (lane = q): softmax state
  float sip = s_i[b*N_+p];
  float L = -3.0e38f;
  if(lane < N_) L = leaky(sip + s_j[b*N_+lane]);
  float M = wmax(L);
  float e = (lane < N_) ? expf(L - M) : 0.f;
  float Dden = wsum(e);
  el[w*64+lane] = e;
  // Phase B (lane = d): S_d = sum_q e_q hR[q][d]  (coalesced, conflict-free)
  float S = 0.f;
#pragma unroll
  for(int q=0;q<N_;q++){
    float eq = rdl(e, q);
    S = fmaf(eq, hR[q*65+lane], S);
  }
  float Em = emb[p*D_+lane]*hci2g[lane];
  // Phase C (lane = sm): serial 64-d head; S/Em via readlane, hc4 scalar
  float er = 0.f; int r = 0;
  if(lane >= 1 && lane < N_){
    int s = lane-1; r = s + (s>=p ? 1 : 0); er = el[w*64+r];
  }
  float beta  = 1.f/(Dden - er);
  float alpha = er*beta;
  float a_ = out_b[0];
#pragma unroll
  for(int d=0;d<64;d++){
    float4 hc = hc4[d];             // uniform -> s_load
    float Sd  = rdl(S,  d);
    float Emd = rdl(Em, d);
    float hrd = hR[r*65 + d];       // lane-varying, <=2-way
    float o  = fmaf(-alpha, hrd, Sd*beta);
    float g  = fmaxf(fmaf(hc.x, o, hc.y), 0.f);
    float xn = fmaxf(fmaf(g, Emd, hc.z), 0.f);
    a_ = fmaf(xn, hc.w, a_);
  }
  if(lane < N_){
    float resid = labels[b*N_+p] - a_;
    atomicAdd(&acc[p*N_+lane].x, resid);
    atomicAdd(&acc[p*N_+lane].y, resid*resid);
  }
}

// K4a: inline F-test -> keep bits; masked attention -> out_raw; Σo,Σo² atomics.
__global__ __launch_bounds__(512) void k4a_out(
    const float* __restrict__ h, const float* __restrict__ s_i,
    const float* __restrict__ s_j, const float2* __restrict__ acc,
    const float* __restrict__ gat_bias,
    float* __restrict__ out_raw, float* __restrict__ stats1){
  __shared__ float hR[N_*65];
  __shared__ int   keepL[8*64];
  __shared__ float2 red[8][64];
  int b = blockIdx.y, tid = threadIdx.x;
  const float* hb = h + (size_t)b*N_*D_;
  for(int i=tid;i<N_*D_;i+=512) hR[(i>>6)*65 + (i&63)] = hb[i];
  __syncthreads();
  int w = tid>>6, lane = tid&63;
  int p = blockIdx.x*8 + w;
  bool act = (p < N_);
  float o = 0.f;
  if(act){
    int kb = 1;
    if(lane < N_-1){
      float2 A2 = acc[p*N_ + lane + 1];
      float2 B2 = acc[p*N_];
      float ma = A2.x*(1.f/B_), mb = B2.x*(1.f/B_);
      float ssw = (A2.y - (float)B_*ma*ma) + (B2.y - (float)B_*mb*mb);
      float dmb = ma - mb;
      float f = (64.f*dmb*dmb) / (ssw*(1.f/254.f));
      kb = (f < FCRIT) ? 0 : 1;     // NaN -> keep (matches reference)
    }
    keepL[w*64+lane] = kb;          // same-wave write/read
    float sip = s_i[b*N_+p];
    float L = -3.0e38f; bool allowed = false;
    if(lane < N_){
      float Lr = leaky(sip + s_j[b*N_+lane]);
      if(lane == p) allowed = true;
      else { int idx = (lane < p) ? lane : lane-1; allowed = keepL[w*64+idx] != 0; }
      L = allowed ? Lr : -1.0e9f;
    }
    float M = wmax(L);
    float e = allowed ? expf(L - M) : 0.f;
    float Dn = wsum(e);
    float invD = 1.f/Dn;
    float s = 0.f;
#pragma unroll
    for(int q=0;q<N_;q++){
      float eq = rdl(e, q);
      s = fmaf(eq, hR[q*65+lane], s);
    }
    o = fmaf(s, invD, gat_bias[lane]);
    out_raw[((size_t)b*N_+p)*D_ + lane] = o;
  }
  red[w][lane] = act ? make_float2(o, o*o) : make_float2(0.f, 0.f);
  __syncthreads();
  if(w==0){
    float a1=0.f, a2=0.f;
#pragma unroll
    for(int k=0;k<8;k++){ float2 v = red[k][lane]; a1+=v.x; a2+=v.y; }
    int slot = b & 7;
    atomicAdd(&stats1[slot*128 + lane],      a1);
    atomicAdd(&stats1[slot*128 + 64 + lane], a2);
  }
}

// K4b: x3-stats pass (needs global mu1/var1 from stats1) -> stats2 slots
__global__ __launch_bounds__(256) void k4b_stats(
    const float* __restrict__ out_raw, const float* __restrict__ emb,
    const float* __restrict__ bn1_g, const float* __restrict__ bn1_b,
    const float* __restrict__ stats1, float* __restrict__ stats2){
  __shared__ float2 red[4][64];
  int tid = threadIdx.x, w = tid>>6, lane = tid&63;
  float t1=0.f, t2=0.f;
#pragma unroll
  for(int k=0;k<8;k++){ t1 += stats1[k*128+lane]; t2 += stats1[k*128+64+lane]; }
  float mu1  = t1*(1.f/BN);
  float var1 = t2*(1.f/BN) - mu1*mu1;
  float A = bn1_g[lane]/sqrtf(var1+EPSF);
  float C = bn1_b[lane] - mu1*A;
  int r0 = blockIdx.x*64;
  float s1=0.f, s2=0.f;
  for(int i=w;i<64;i+=4){
    int r = r0+i;
    float o = out_raw[(size_t)r*D_ + lane];
    float g = fmaxf(fmaf(A,o,C), 0.f);
    float x3 = g*emb[(r%N_)*D_ + lane];
    s1 += x3; s2 = fmaf(x3,x3,s2);
  }
  red[w][lane] = make_float2(s1,s2);
  __syncthreads();
  if(w==0){
    float2 a=red[0][lane], b=red[1][lane], c=red[2][lane], d=red[3][lane];
    int slot = blockIdx.x & 7;
    atomicAdd(&stats2[slot*128 + lane],      a.x+b.x+c.x+d.x);
    atomicAdd(&stats2[slot*128 + 64 + lane], a.y+b.y+c.y+d.y);
  }
}

// K4c: final head -> d_out[b*N+p]; 16 rows/block
__global__ __launch_bounds__(256) void k4c_final(
    const float* __restrict__ out_raw, const float* __restrict__ emb,
    const float* __restrict__ bn1_g, const float* __restrict__ bn1_b,
    const float* __restrict__ bn2_g, const float* __restrict__ bn2_b,
    const float* __restrict__ out_w, const float* __restrict__ out_b,
    const float* __restrict__ stats1, const float* __restrict__ stats2,
    float* __restrict__ outp){
  int tid = threadIdx.x, w = tid>>6, lane = tid&63;
  float t1=0.f, t2=0.f, t3=0.f, t4=0.f;
#pragma unroll
  for(int k=0;k<8;k++){
    t1 += stats1[k*128+lane]; t2 += stats1[k*128+64+lane];
    t3 += stats2[k*128+lane]; t4 += stats2[k*128+64+lane];
  }
  float mu1  = t1*(1.f/BN), var1 = t2*(1.f/BN) - mu1*mu1;
  float mu2  = t3*(1.f/BN), var2 = t4*(1.f/BN) - mu2*mu2;
  float A1 = bn1_g[lane]/sqrtf(var1+EPSF);
  float C1 = bn1_b[lane] - mu1*A1;
  float A2 = bn2_g[lane]/sqrtf(var2+EPSF);
  float C2 = bn2_b[lane] - mu2*A2;
  float ow = out_w[lane], ob = out_b[0];
#pragma unroll
  for(int j=0;j<4;j++){
    int r = blockIdx.x*16 + w*4 + j;
    float o = out_raw[(size_t)r*D_ + lane];
    float g = fmaxf(fmaf(A1,o,C1), 0.f);
    float x3 = g*emb[(r%N_)*D_ + lane];
    float xn = fmaxf(fmaf(A2,x3,C2), 0.f);
    float pr = wsum(xn*ow);
    if(lane==0) outp[r] = pr + ob;
  }
}

extern "C" void kernel_launch(void* const* d_in, const int* in_sizes, int n_in,
                              void* d_out, int out_size, void* d_ws, size_t ws_size,
                              hipStream_t stream){
  (void)in_sizes; (void)n_in; (void)out_size; (void)ws_size;
  const float* data     = (const float*)d_in[0];
  const float* labels   = (const float*)d_in[1];
  // d_in[2..6]: graph indices / masks — deterministic, not read.
  const float* emb      = (const float*)d_in[7];
  const float* W_lin    = (const float*)d_in[8];
  const float* att_i    = (const float*)d_in[9];
  const float* att_j    = (const float*)d_in[10];
  const float* att_em_i = (const float*)d_in[11];
  const float* att_em_j = (const float*)d_in[12];
  const float* gat_bias = (const float*)d_in[13];
  const float* bn1_g    = (const float*)d_in[14];
  const float* bn1_b    = (const float*)d_in[15];
  const float* bn1_rm   = (const float*)d_in[16];
  const float* bn1_rv   = (const float*)d_in[17];
  const float* bn2_g    = (const float*)d_in[18];
  const float* bn2_b    = (const float*)d_in[19];
  const float* bn2_rm   = (const float*)d_in[20];
  const float* bn2_rv   = (const float*)d_in[21];
  const float* out_w    = (const float*)d_in[22];
  const float* out_b    = (const float*)d_in[23];

  float*  ws      = (float*)d_ws;
  float*  h       = ws;                      // 409600
  float*  s_i     = ws + 409600;             // 6400
  float*  s_j     = ws + 416000;             // 6400
  float*  out_raw = ws + 422400;             // 409600 -> 832000
  float2* acc     = (float2*)(ws + 832000);  // 2500 float2 -> 837000
  float*  stats1  = ws + 837000;             // 1024 -> 838024
  float*  stats2  = ws + 838024;             // 1024 -> 839048
  float4* hc4     = (float4*)(ws + 839048);  // 64 float4 (16B-aligned)
  float*  hci2g   = ws + 839304;             // 64
  float*  outp    = (float*)d_out;

  hipLaunchKernelGGL(k1_lin, dim3(BN/8), dim3(256), 0, stream,
                     data, W_lin, emb, att_i, att_j, att_em_i, att_em_j,
                     bn1_g, bn1_b, bn1_rm, bn1_rv, bn2_g, bn2_b, bn2_rm, bn2_rv,
                     gat_bias, out_w, h, s_i, s_j, acc, stats1, hc4, hci2g);
  hipLaunchKernelGGL(k2_preds, dim3(7, B_), dim3(512), 0, stream,
                     h, s_i, s_j, labels, emb, out_b, hc4, hci2g, acc);
  hipLaunchKernelGGL(k4a_out, dim3(7, B_), dim3(512), 0, stream,
                     h, s_i, s_j, acc, gat_bias, out_raw, stats1);
  hipLaunchKernelGGL(k4b_stats, dim3(BN/64), dim3(256), 0, stream,
                     out_raw, emb, bn1_g, bn1_b, stats1, stats2);
  hipLaunchKernelGGL(k4c_final, dim3(BN/16), dim3(256), 0, stream,
                     out_raw, emb, bn1_g, bn1_b, bn2_g, bn2_b, out_w, out_b,
                     stats1, stats2, outp);
}